// Round 1
// baseline (3952.942 us; speedup 1.0000x reference)
//
#include <hip/hip_runtime.h>
#include <cstdint>
#include <cstddef>

#define B_ 4
#define V1 262144   // 64^3
#define C1 64
#define V2 32768    // 32^3
#define C2 128

// ws layout (float offsets)
#define OFF_S1A 0
#define OFF_S2A 128
#define OFF_CNT1 256
#define OFF_S1B 260
#define OFF_S2B 388
#define OFF_CNT2 516
#define OFF_H1  1024
#define OFF_XD  (OFF_H1 + (size_t)B_*V2*C1)
#define OFF_DM  (OFF_XD + (size_t)B_*V2*C1)
#define OFF_H2  (OFF_DM + (size_t)B_*V2)

// ---------------- Kernel 1: GN1 stats (sum, sumsq per (b,group)) + mask count per b ----------------
__global__ __launch_bounds__(256) void k1_stats1(const float* __restrict__ x,
                                                 const int* __restrict__ mask,
                                                 float* __restrict__ ws)
{
    __shared__ float ls1[32], ls2[32];
    __shared__ float lcnt;
    int tid = threadIdx.x;
    if (tid < 32) { ls1[tid] = 0.f; ls2[tid] = 0.f; }
    if (tid == 0) lcnt = 0.f;
    __syncthreads();

    int b  = blockIdx.x & 3;
    int bb = blockIdx.x >> 2;          // 0..1023
    int c4 = tid & 15;                 // which float4 of the 64 channels
    int vl = tid >> 4;                 // voxel within 16-voxel chunk

    const float* xb = x + ((size_t)b * V1) * C1;
    const int*   mb = mask + (size_t)b * V1;

    float s1a = 0.f, s2a = 0.f, s1b = 0.f, s2b = 0.f, mc = 0.f;
    for (int ch = bb; ch < V1 / 16; ch += 1024) {
        int v = ch * 16 + vl;
        int m = mb[v];
        if (c4 == 0) mc += (float)m;
        if (m) {
            float4 xv = *(const float4*)(xb + (size_t)v * C1 + c4 * 4);
            s1a += xv.x + xv.y;  s2a += xv.x * xv.x + xv.y * xv.y;
            s1b += xv.z + xv.w;  s2b += xv.z * xv.z + xv.w * xv.w;
        }
    }
    atomicAdd(&ls1[2 * c4],     s1a); atomicAdd(&ls2[2 * c4],     s2a);
    atomicAdd(&ls1[2 * c4 + 1], s1b); atomicAdd(&ls2[2 * c4 + 1], s2b);
    if (c4 == 0) atomicAdd(&lcnt, mc);
    __syncthreads();
    if (tid < 32) {
        atomicAdd(&ws[OFF_S1A + b * 32 + tid], ls1[tid]);
        atomicAdd(&ws[OFF_S2A + b * 32 + tid], ls2[tid]);
    }
    if (tid == 0) atomicAdd(&ws[OFF_CNT1 + b], lcnt);
}

// ------ Kernel 2: GN1 apply + SiLU + downsample (h path), downsample raw masked x (skip path), dm ------
__global__ __launch_bounds__(256) void k2_down(const float* __restrict__ x,
                                               const int* __restrict__ mask,
                                               const float* __restrict__ gn1w,
                                               const float* __restrict__ gn1b,
                                               float* __restrict__ ws)
{
    int tid = threadIdx.x;
    int c  = tid & 63;
    int vl = tid >> 6;
    size_t ov = (size_t)blockIdx.x * 4 + vl;     // 0 .. B*V2-1
    int b  = (int)(ov >> 15);
    int v2 = (int)(ov & 32767);
    int z = v2 >> 10, y = (v2 >> 5) & 31, xk = v2 & 31;

    int g = c >> 1;
    float ce   = fmaxf(ws[OFF_CNT1 + b] * 2.f, 1.f);
    float mean = ws[OFF_S1A + b * 32 + g] / ce;
    float var  = ws[OFF_S2A + b * 32 + g] / ce - mean * mean;
    float rinv = rsqrtf(var + 1e-5f);
    float a  = rinv * gn1w[c];
    float bc = gn1b[c] - mean * a;

    const int*   mb = mask + ((size_t)b << 18);
    const float* xb = x + (((size_t)b << 18) << 6);

    float hacc = 0.f, xacc = 0.f; int cnt = 0;
    #pragma unroll
    for (int dz = 0; dz < 2; ++dz)
    #pragma unroll
    for (int dy = 0; dy < 2; ++dy)
    #pragma unroll
    for (int dx = 0; dx < 2; ++dx) {
        int v1 = ((2 * z + dz) << 12) | ((2 * y + dy) << 6) | (2 * xk + dx);
        if (mb[v1]) {
            cnt++;
            float xv = xb[(size_t)v1 * 64 + c];
            xacc += xv;
            float yv = fmaf(xv, a, bc);
            hacc += yv / (1.f + expf(-yv));
        }
    }
    float inv = 1.f / fmaxf((float)cnt, 1.f);
    ws[OFF_H1 + ov * 64 + c] = hacc * inv;
    ws[OFF_XD + ov * 64 + c] = xacc * inv;
    if (c == 0) ws[OFF_DM + ov] = (cnt > 0) ? 1.f : 0.f;
}

// ---------------- Kernel 3: conv1 3x3x3, 64 -> 128, SAME, masked output ----------------
// One block per (b, z, y) output row of 32 voxels. 256 threads = 128 co x 2 halves (16 voxels each).
__global__ __launch_bounds__(256) void k3_conv1(float* __restrict__ ws,
                                                const float* __restrict__ w1,
                                                const float* __restrict__ b1)
{
    __shared__ float s[34 * 64];
    int tid = threadIdx.x;
    int co = tid & 127, half = tid >> 7;
    int blk = blockIdx.x;
    int b = blk >> 10, row = blk & 1023;
    int z = row >> 5, y = row & 31;

    const float* h1 = ws + OFF_H1;
    const float* dm = ws + OFF_DM;
    float* h2 = ws + OFF_H2;

    float acc[16];
    #pragma unroll
    for (int j = 0; j < 16; ++j) acc[j] = 0.f;

    for (int dz = 0; dz < 3; ++dz) {
        int zz = z + dz - 1;
        for (int dy = 0; dy < 3; ++dy) {
            int yy = y + dy - 1;
            bool rowok = ((unsigned)zz < 32u) && ((unsigned)yy < 32u);
            const float* src = h1 + ((size_t)b * 32768 + (size_t)(zz * 1024 + yy * 32)) * 64;
            __syncthreads();
            for (int i = tid; i < 34 * 16; i += 256) {
                int xx = (i >> 4) - 1, c4 = i & 15;
                float4 v = make_float4(0.f, 0.f, 0.f, 0.f);
                if (rowok && (unsigned)xx < 32u)
                    v = *(const float4*)(src + (size_t)xx * 64 + c4 * 4);
                *(float4*)(s + (i >> 4) * 64 + c4 * 4) = v;
            }
            __syncthreads();
            for (int dx = 0; dx < 3; ++dx) {
                const float* wp = w1 + (size_t)(((dz * 3 + dy) * 3 + dx) * 64) * 128 + co;
                for (int c4 = 0; c4 < 16; ++c4) {
                    float w0 = wp[(c4 * 4 + 0) * 128];
                    float w1v = wp[(c4 * 4 + 1) * 128];
                    float w2v = wp[(c4 * 4 + 2) * 128];
                    float w3v = wp[(c4 * 4 + 3) * 128];
                    #pragma unroll
                    for (int j = 0; j < 16; ++j) {
                        const float4 iv = *(const float4*)(s + (half * 16 + j + dx) * 64 + c4 * 4);
                        acc[j] = fmaf(iv.x, w0,  acc[j]);
                        acc[j] = fmaf(iv.y, w1v, acc[j]);
                        acc[j] = fmaf(iv.z, w2v, acc[j]);
                        acc[j] = fmaf(iv.w, w3v, acc[j]);
                    }
                }
            }
        }
    }
    size_t ovbase = (size_t)b * 32768 + (size_t)(z * 1024 + y * 32);
    float bias = b1[co];
    #pragma unroll
    for (int j = 0; j < 16; ++j) {
        size_t ov = ovbase + half * 16 + j;
        h2[ov * 128 + co] = (acc[j] + bias) * dm[ov];
    }
}

// ---------------- Kernel 4: GN2 stats over h2 ----------------
__global__ __launch_bounds__(256) void k4_stats2(float* __restrict__ ws)
{
    __shared__ float ls1[32], ls2[32];
    __shared__ float lcnt;
    int tid = threadIdx.x;
    if (tid < 32) { ls1[tid] = 0.f; ls2[tid] = 0.f; }
    if (tid == 0) lcnt = 0.f;
    __syncthreads();

    int b  = blockIdx.x & 3;
    int bb = blockIdx.x >> 2;
    int c4 = tid & 31;     // group index (Cg=4 => one float4 per group)
    int vl = tid >> 5;     // 8 voxels per chunk

    const float* h2 = ws + OFF_H2 + ((size_t)b * V2) * C2;
    const float* dm = ws + OFF_DM + (size_t)b * V2;

    float s1 = 0.f, s2 = 0.f, mc = 0.f;
    for (int ch = bb; ch < V2 / 8; ch += 1024) {
        int v = ch * 8 + vl;
        float m = dm[v];
        if (c4 == 0) mc += m;
        if (m != 0.f) {
            float4 hv = *(const float4*)(h2 + (size_t)v * C2 + c4 * 4);
            s1 += hv.x + hv.y + hv.z + hv.w;
            s2 += hv.x * hv.x + hv.y * hv.y + hv.z * hv.z + hv.w * hv.w;
        }
    }
    atomicAdd(&ls1[c4], s1); atomicAdd(&ls2[c4], s2);
    if (c4 == 0) atomicAdd(&lcnt, mc);
    __syncthreads();
    if (tid < 32) {
        atomicAdd(&ws[OFF_S1B + b * 32 + tid], ls1[tid]);
        atomicAdd(&ws[OFF_S2B + b * 32 + tid], ls2[tid]);
    }
    if (tid == 0) atomicAdd(&ws[OFF_CNT2 + b], lcnt);
}

// ---------------- Kernel 5: GN2 apply + SiLU (in place on h2) ----------------
__global__ __launch_bounds__(256) void k5_gn2(float* __restrict__ ws,
                                              const float* __restrict__ gn2w,
                                              const float* __restrict__ gn2b)
{
    int idx = blockIdx.x * 256 + threadIdx.x;   // 0 .. B*V2*32-1 (float4 index)
    int v = idx >> 5, c4 = idx & 31;
    int b = v >> 15;
    float ce   = fmaxf(ws[OFF_CNT2 + b] * 4.f, 1.f);
    float mean = ws[OFF_S1B + b * 32 + c4] / ce;
    float var  = ws[OFF_S2B + b * 32 + c4] / ce - mean * mean;
    float rinv = rsqrtf(var + 1e-5f);
    float dmv  = ws[OFF_DM + v];
    float4 g4 = *(const float4*)(gn2w + c4 * 4);
    float4 b4 = *(const float4*)(gn2b + c4 * 4);
    float* p = ws + OFF_H2 + (size_t)idx * 4;
    float4 h = *(float4*)p;
    float a, t;
    a = rinv * g4.x; t = (fmaf(h.x, a, b4.x - mean * a)) * dmv; h.x = t / (1.f + expf(-t));
    a = rinv * g4.y; t = (fmaf(h.y, a, b4.y - mean * a)) * dmv; h.y = t / (1.f + expf(-t));
    a = rinv * g4.z; t = (fmaf(h.z, a, b4.z - mean * a)) * dmv; h.z = t / (1.f + expf(-t));
    a = rinv * g4.w; t = (fmaf(h.w, a, b4.w - mean * a)) * dmv; h.w = t / (1.f + expf(-t));
    *(float4*)p = h;
}

// ---------------- Kernel 6: conv2 3x3x3 128->128 + 1x1 skip + biases, masked ----------------
__global__ __launch_bounds__(256) void k6_conv2(const float* __restrict__ ws,
                                                const float* __restrict__ w2,
                                                const float* __restrict__ b2,
                                                const float* __restrict__ wskip,
                                                const float* __restrict__ bskip,
                                                float* __restrict__ out)
{
    __shared__ float s[34 * 128];
    int tid = threadIdx.x;
    int co = tid & 127, half = tid >> 7;
    int blk = blockIdx.x;
    int b = blk >> 10, row = blk & 1023;
    int z = row >> 5, y = row & 31;

    const float* h2 = ws + OFF_H2;
    const float* dm = ws + OFF_DM;
    const float* xd = ws + OFF_XD;

    float acc[16];
    #pragma unroll
    for (int j = 0; j < 16; ++j) acc[j] = 0.f;

    for (int dz = 0; dz < 3; ++dz) {
        int zz = z + dz - 1;
        for (int dy = 0; dy < 3; ++dy) {
            int yy = y + dy - 1;
            bool rowok = ((unsigned)zz < 32u) && ((unsigned)yy < 32u);
            const float* src = h2 + ((size_t)b * 32768 + (size_t)(zz * 1024 + yy * 32)) * 128;
            __syncthreads();
            for (int i = tid; i < 34 * 32; i += 256) {
                int xx = (i >> 5) - 1, c4 = i & 31;
                float4 v = make_float4(0.f, 0.f, 0.f, 0.f);
                if (rowok && (unsigned)xx < 32u)
                    v = *(const float4*)(src + (size_t)xx * 128 + c4 * 4);
                *(float4*)(s + (i >> 5) * 128 + c4 * 4) = v;
            }
            __syncthreads();
            for (int dx = 0; dx < 3; ++dx) {
                const float* wp = w2 + (size_t)(((dz * 3 + dy) * 3 + dx) * 128) * 128 + co;
                for (int c4 = 0; c4 < 32; ++c4) {
                    float w0 = wp[(c4 * 4 + 0) * 128];
                    float w1v = wp[(c4 * 4 + 1) * 128];
                    float w2v = wp[(c4 * 4 + 2) * 128];
                    float w3v = wp[(c4 * 4 + 3) * 128];
                    #pragma unroll
                    for (int j = 0; j < 16; ++j) {
                        const float4 iv = *(const float4*)(s + (half * 16 + j + dx) * 128 + c4 * 4);
                        acc[j] = fmaf(iv.x, w0,  acc[j]);
                        acc[j] = fmaf(iv.y, w1v, acc[j]);
                        acc[j] = fmaf(iv.z, w2v, acc[j]);
                        acc[j] = fmaf(iv.w, w3v, acc[j]);
                    }
                }
            }
        }
    }

    // skip path: xd[v, 0..63] @ wskip[64,128]
    size_t ovbase = (size_t)b * 32768 + (size_t)(z * 1024 + y * 32);
    __syncthreads();
    {
        const float* xsrc = xd + ovbase * 64;
        for (int i = tid; i < 512; i += 256)
            ((float4*)s)[i] = ((const float4*)xsrc)[i];
    }
    __syncthreads();
    {
        const float* wsp = wskip + co;
        for (int c4 = 0; c4 < 16; ++c4) {
            float w0 = wsp[(c4 * 4 + 0) * 128];
            float w1v = wsp[(c4 * 4 + 1) * 128];
            float w2v = wsp[(c4 * 4 + 2) * 128];
            float w3v = wsp[(c4 * 4 + 3) * 128];
            #pragma unroll
            for (int j = 0; j < 16; ++j) {
                const float4 iv = *(const float4*)(s + (half * 16 + j) * 64 + c4 * 4);
                acc[j] = fmaf(iv.x, w0,  acc[j]);
                acc[j] = fmaf(iv.y, w1v, acc[j]);
                acc[j] = fmaf(iv.z, w2v, acc[j]);
                acc[j] = fmaf(iv.w, w3v, acc[j]);
            }
        }
    }

    float bias = b2[co] + bskip[co];
    #pragma unroll
    for (int j = 0; j < 16; ++j) {
        size_t ov = ovbase + half * 16 + j;
        out[ov * 128 + co] = (acc[j] + bias) * dm[ov];
    }
}

extern "C" void kernel_launch(void* const* d_in, const int* in_sizes, int n_in,
                              void* d_out, int out_size, void* d_ws, size_t ws_size,
                              hipStream_t stream)
{
    const float* x     = (const float*)d_in[0];
    const int*   mask  = (const int*)d_in[1];
    const float* gn1w  = (const float*)d_in[2];
    const float* gn1b  = (const float*)d_in[3];
    const float* w1    = (const float*)d_in[4];
    const float* b1    = (const float*)d_in[5];
    const float* gn2w  = (const float*)d_in[6];
    const float* gn2b  = (const float*)d_in[7];
    const float* w2    = (const float*)d_in[8];
    const float* b2    = (const float*)d_in[9];
    const float* wskip = (const float*)d_in[10];
    const float* bskip = (const float*)d_in[11];
    float* ws  = (float*)d_ws;
    float* out = (float*)d_out;

    // zero the stats accumulators (atomicAdd targets)
    hipMemsetAsync(d_ws, 0, 520 * sizeof(float), stream);

    hipLaunchKernelGGL(k1_stats1, dim3(4096),  dim3(256), 0, stream, x, mask, ws);
    hipLaunchKernelGGL(k2_down,   dim3(32768), dim3(256), 0, stream, x, mask, gn1w, gn1b, ws);
    hipLaunchKernelGGL(k3_conv1,  dim3(4096),  dim3(256), 0, stream, ws, w1, b1);
    hipLaunchKernelGGL(k4_stats2, dim3(4096),  dim3(256), 0, stream, ws);
    hipLaunchKernelGGL(k5_gn2,    dim3(16384), dim3(256), 0, stream, ws, gn2w, gn2b);
    hipLaunchKernelGGL(k6_conv2,  dim3(4096),  dim3(256), 0, stream, ws, w2, b2, wskip, bskip, out);
}

// Round 3
// 475.218 us; speedup vs baseline: 8.3182x; 8.3182x over previous
//
#include <hip/hip_runtime.h>
#include <cstdint>
#include <cstddef>

#define B_ 4
#define V1 262144   // 64^3
#define C1 64
#define V2 32768    // 32^3
#define C2 128

// stats layout (float indices within stats buffer)
#define OFF_S1A 0
#define OFF_S2A 128
#define OFF_CNT1 256
#define OFF_S1B 260
#define OFF_S2B 388
#define OFF_CNT2 516

typedef __bf16 bf16x8 __attribute__((ext_vector_type(8)));
typedef float f32x4 __attribute__((ext_vector_type(4)));

__device__ __forceinline__ float bf2f(unsigned short u) {
    return __builtin_bit_cast(float, (unsigned)u << 16);
}
__device__ __forceinline__ unsigned short f2bf(float f) {
    unsigned u = __builtin_bit_cast(unsigned, f);
    u += 0x7fffu + ((u >> 16) & 1u);     // RTNE
    return (unsigned short)(u >> 16);
}

// ---------------- Kernel 0: weight prep -> bf16, frag-contiguous slabs [q][n][j] ----------------
// W1T: 54 slabs (27 taps x 2 cslices). W2T: 110 slabs (27x4 conv2 + 2 skip).
__global__ __launch_bounds__(256) void k0_wprep(const float* __restrict__ w1,
                                                const float* __restrict__ w2,
                                                const float* __restrict__ wskip,
                                                unsigned short* __restrict__ w1t,
                                                unsigned short* __restrict__ w2t)
{
    int i = blockIdx.x * 256 + threadIdx.x;
    if (i < 54 * 4096) {
        int slab = i >> 12, r = i & 4095;
        int q = r >> 10, n = (r >> 3) & 127, j = r & 7;
        int t = slab >> 1, s = slab & 1;
        int ci = s * 32 + q * 8 + j;
        w1t[i] = f2bf(w1[((size_t)t * 64 + ci) * 128 + n]);
    }
    int i2 = i - 54 * 4096;
    if (i2 >= 0 && i2 < 110 * 4096) {
        int slab = i2 >> 12, r = i2 & 4095;
        int q = r >> 10, n = (r >> 3) & 127, j = r & 7;
        float v;
        if (slab < 108) {
            int t = slab >> 2, s = slab & 3;
            int ci = s * 32 + q * 8 + j;
            v = w2[((size_t)t * 128 + ci) * 128 + n];
        } else {
            int ci = (slab - 108) * 32 + q * 8 + j;
            v = wskip[(size_t)ci * 128 + n];
        }
        w2t[i2] = f2bf(v);
    }
}

// ---------------- Kernel 1: GN1 stats ----------------
__global__ __launch_bounds__(256) void k1_stats1(const float* __restrict__ x,
                                                 const int* __restrict__ mask,
                                                 float* __restrict__ stats)
{
    __shared__ float ls1[32], ls2[32];
    __shared__ float lcnt;
    int tid = threadIdx.x;
    if (tid < 32) { ls1[tid] = 0.f; ls2[tid] = 0.f; }
    if (tid == 0) lcnt = 0.f;
    __syncthreads();

    int b  = blockIdx.x & 3;
    int bb = blockIdx.x >> 2;
    int c4 = tid & 15;
    int vl = tid >> 4;

    const float* xb = x + ((size_t)b * V1) * C1;
    const int*   mb = mask + (size_t)b * V1;

    float s1a = 0.f, s2a = 0.f, s1b = 0.f, s2b = 0.f, mc = 0.f;
    for (int ch = bb; ch < V1 / 16; ch += 1024) {
        int v = ch * 16 + vl;
        int m = mb[v];
        if (c4 == 0) mc += (float)m;
        if (m) {
            float4 xv = *(const float4*)(xb + (size_t)v * C1 + c4 * 4);
            s1a += xv.x + xv.y;  s2a += xv.x * xv.x + xv.y * xv.y;
            s1b += xv.z + xv.w;  s2b += xv.z * xv.z + xv.w * xv.w;
        }
    }
    atomicAdd(&ls1[2 * c4],     s1a); atomicAdd(&ls2[2 * c4],     s2a);
    atomicAdd(&ls1[2 * c4 + 1], s1b); atomicAdd(&ls2[2 * c4 + 1], s2b);
    if (c4 == 0) atomicAdd(&lcnt, mc);
    __syncthreads();
    if (tid < 32) {
        atomicAdd(&stats[OFF_S1A + b * 32 + tid], ls1[tid]);
        atomicAdd(&stats[OFF_S2A + b * 32 + tid], ls2[tid]);
    }
    if (tid == 0) atomicAdd(&stats[OFF_CNT1 + b], lcnt);
}

// ------ Kernel 2: GN1 apply + SiLU + downsample -> h1b (bf16), xd -> xdb (bf16), dm ------
__global__ __launch_bounds__(256) void k2_down(const float* __restrict__ x,
                                               const int* __restrict__ mask,
                                               const float* __restrict__ gn1w,
                                               const float* __restrict__ gn1b,
                                               const float* __restrict__ stats,
                                               unsigned short* __restrict__ h1b,
                                               unsigned short* __restrict__ xdb,
                                               float* __restrict__ dm)
{
    int tid = threadIdx.x;
    int c  = tid & 63;
    int vl = tid >> 6;
    size_t ov = (size_t)blockIdx.x * 4 + vl;
    int b  = (int)(ov >> 15);
    int v2 = (int)(ov & 32767);
    int z = v2 >> 10, y = (v2 >> 5) & 31, xk = v2 & 31;

    int g = c >> 1;
    float ce   = fmaxf(stats[OFF_CNT1 + b] * 2.f, 1.f);
    float mean = stats[OFF_S1A + b * 32 + g] / ce;
    float var  = stats[OFF_S2A + b * 32 + g] / ce - mean * mean;
    float rinv = rsqrtf(var + 1e-5f);
    float a  = rinv * gn1w[c];
    float bc = gn1b[c] - mean * a;

    const int*   mb = mask + ((size_t)b << 18);
    const float* xb = x + (((size_t)b << 18) << 6);

    float hacc = 0.f, xacc = 0.f; int cnt = 0;
    #pragma unroll
    for (int dz = 0; dz < 2; ++dz)
    #pragma unroll
    for (int dy = 0; dy < 2; ++dy)
    #pragma unroll
    for (int dx = 0; dx < 2; ++dx) {
        int v1 = ((2 * z + dz) << 12) | ((2 * y + dy) << 6) | (2 * xk + dx);
        if (mb[v1]) {
            cnt++;
            float xv = xb[(size_t)v1 * 64 + c];
            xacc += xv;
            float yv = fmaf(xv, a, bc);
            hacc += yv / (1.f + expf(-yv));
        }
    }
    float inv = 1.f / fmaxf((float)cnt, 1.f);
    h1b[ov * 64 + c] = f2bf(hacc * inv);
    xdb[ov * 64 + c] = f2bf(xacc * inv);
    if (c == 0) dm[ov] = (cnt > 0) ? 1.f : 0.f;
}

// ---------------- MFMA implicit-GEMM conv 3x3x3 (+optional 1x1 skip taps) ----------------
// Block: 256 thr = 4 waves. Block tile: M=256 voxels (8 y-rows at one (b,z)), N=128.
// Wave: M=64 (2 y-rows), N=128 -> acc[4][8] f32x4 (128 VGPR).
// B staged per K-step (8KB slab) in LDS, double-buffered, reg-staged (T14 issue-early/write-late).
template<int CIN, bool SKIP>
__global__ __launch_bounds__(256, 2) void conv3_mfma(
    const unsigned short* __restrict__ src,
    const unsigned short* __restrict__ sksrc,
    const unsigned short* __restrict__ wT,
    const float* __restrict__ bias,
    const float* __restrict__ bias2,
    const float* __restrict__ dm,
    float* __restrict__ outf,
    unsigned short* __restrict__ outb)
{
    constexpr int CS  = CIN / 32;
    constexpr int NKM = 27 * CS;
    constexpr int NK  = NKM + (SKIP ? 2 : 0);

    __shared__ short smem[2][4096];   // 2 x 8KB weight slabs

    const int tid  = threadIdx.x;
    const int lane = tid & 63;
    const int wv   = tid >> 6;
    const int blk  = blockIdx.x;
    const int b    = blk >> 7;
    const int z    = (blk >> 2) & 31;
    const int yo   = blk & 3;
    const int y0   = yo * 8 + wv * 2;
    const int vb   = b * 32768;
    const int klo  = (lane >> 4) * 8;
    const int xl   = lane & 15;
    const int rlo  = (lane >> 4) * 4;

    const uint4* wT4 = (const uint4*)wT;
    uint4* sm4 = (uint4*)&smem[0][0];

    f32x4 acc[4][8];
    #pragma unroll
    for (int f = 0; f < 4; ++f)
        #pragma unroll
        for (int nb = 0; nb < 8; ++nb)
            acc[f][nb] = (f32x4){0.f, 0.f, 0.f, 0.f};

    // prologue: stage slab 0
    {
        uint4 p0 = wT4[tid], p1 = wT4[tid + 256];
        sm4[tid] = p0; sm4[tid + 256] = p1;
        __syncthreads();
    }
    int cur = 0;
    int ks  = 0;

    auto kstep = [&](const unsigned short* abase, int cinl, int zz, int dy, int dx,
                     bool zok, bool isskip) {
        // T14: issue next-slab loads early
        uint4 q0, q1;
        bool pf = (ks + 1) < NK;
        if (pf) {
            q0 = wT4[(size_t)(ks + 1) * 512 + tid];
            q1 = wT4[(size_t)(ks + 1) * 512 + 256 + tid];
        }
        // A fragments (global, per-lane predicated)
        bf16x8 af[4];
        #pragma unroll
        for (int f = 0; f < 4; ++f) {
            int yy = y0 + (f >> 1) + (isskip ? 0 : (dy - 1));
            int xx = (f & 1) * 16 + xl + (isskip ? 0 : (dx - 1));
            bool ok = zok && ((unsigned)yy < 32u) && ((unsigned)xx < 32u);
            bf16x8 a = {};
            const unsigned short* ap =
                abase + (size_t)(vb + zz * 1024 + yy * 32 + xx) * (size_t)cinl + klo;
            if (ok) a = *(const bf16x8*)ap;
            af[f] = a;
        }
        // B from LDS + MFMA
        const int eoffb = cur * 4096 + ((lane >> 4) * 128 + xl) * 8;
        #pragma unroll
        for (int nb = 0; nb < 8; ++nb) {
            bf16x8 bf = *(const bf16x8*)(&smem[0][0] + eoffb + nb * 128);
            #pragma unroll
            for (int f = 0; f < 4; ++f)
                acc[f][nb] = __builtin_amdgcn_mfma_f32_16x16x32_bf16(af[f], bf, acc[f][nb], 0, 0, 0);
        }
        // write-late: next slab into other buffer
        if (pf) {
            sm4[(cur ^ 1) * 512 + tid] = q0;
            sm4[(cur ^ 1) * 512 + 256 + tid] = q1;
        }
        __syncthreads();
        cur ^= 1;
        ++ks;
    };

    #pragma clang loop unroll(disable)
    for (int dz = 0; dz < 3; ++dz) {
        int zz = z + dz - 1;
        bool zok = (unsigned)zz < 32u;
        #pragma clang loop unroll(disable)
        for (int dy = 0; dy < 3; ++dy) {
            #pragma clang loop unroll(disable)
            for (int dx = 0; dx < 3; ++dx) {
                #pragma clang loop unroll(disable)
                for (int s = 0; s < CS; ++s) {
                    kstep(src + s * 32, CIN, zz, dy, dx, zok, false);
                }
            }
        }
    }
    if constexpr (SKIP) {
        kstep(sksrc,      64, z, 0, 0, true, true);
        kstep(sksrc + 32, 64, z, 0, 0, true, true);
    }

    // epilogue
    float bv[8];
    #pragma unroll
    for (int nb = 0; nb < 8; ++nb) {
        int co = nb * 16 + xl;
        if constexpr (SKIP) bv[nb] = bias[co] + bias2[co];
        else                bv[nb] = bias[co];
    }
    #pragma unroll
    for (int f = 0; f < 4; ++f) {
        int yr = y0 + (f >> 1);
        int xb2 = (f & 1) * 16 + rlo;
        #pragma unroll
        for (int j = 0; j < 4; ++j) {
            int vox = vb + z * 1024 + yr * 32 + xb2 + j;
            float dmx = dm[vox];
            #pragma unroll
            for (int nb = 0; nb < 8; ++nb) {
                float o = (acc[f][nb][j] + bv[nb]) * dmx;
                if constexpr (SKIP) outf[(size_t)vox * 128 + nb * 16 + xl] = o;
                else                outb[(size_t)vox * 128 + nb * 16 + xl] = f2bf(o);
            }
        }
    }
}

// ---------------- Kernel 4: GN2 stats over h2a (bf16) ----------------
__global__ __launch_bounds__(256) void k4_stats2(const unsigned short* __restrict__ h2a,
                                                 const float* __restrict__ dm,
                                                 float* __restrict__ stats)
{
    __shared__ float ls1[32], ls2[32];
    __shared__ float lcnt;
    int tid = threadIdx.x;
    if (tid < 32) { ls1[tid] = 0.f; ls2[tid] = 0.f; }
    if (tid == 0) lcnt = 0.f;
    __syncthreads();

    int b  = blockIdx.x & 3;
    int bb = blockIdx.x >> 2;
    int g  = tid & 31;
    int vl = tid >> 5;

    const unsigned short* hb = h2a + ((size_t)b * V2) * C2;
    const float* dmb = dm + (size_t)b * V2;

    float s1 = 0.f, s2 = 0.f, mc = 0.f;
    for (int ch = bb; ch < V2 / 8; ch += 1024) {
        int v = ch * 8 + vl;
        float m = dmb[v];
        if (g == 0) mc += m;
        if (m != 0.f) {
            ushort4 hv = *(const ushort4*)(hb + (size_t)v * C2 + g * 4);
            float h0 = bf2f(hv.x), h1 = bf2f(hv.y), h2 = bf2f(hv.z), h3 = bf2f(hv.w);
            s1 += h0 + h1 + h2 + h3;
            s2 += h0 * h0 + h1 * h1 + h2 * h2 + h3 * h3;
        }
    }
    atomicAdd(&ls1[g], s1); atomicAdd(&ls2[g], s2);
    if (g == 0) atomicAdd(&lcnt, mc);
    __syncthreads();
    if (tid < 32) {
        atomicAdd(&stats[OFF_S1B + b * 32 + tid], ls1[tid]);
        atomicAdd(&stats[OFF_S2B + b * 32 + tid], ls2[tid]);
    }
    if (tid == 0) atomicAdd(&stats[OFF_CNT2 + b], lcnt);
}

// ---------------- Kernel 5: GN2 apply + SiLU -> h2b (bf16) ----------------
__global__ __launch_bounds__(256) void k5_gn2(const unsigned short* __restrict__ h2a,
                                              unsigned short* __restrict__ h2b,
                                              const float* __restrict__ stats,
                                              const float* __restrict__ dm,
                                              const float* __restrict__ gn2w,
                                              const float* __restrict__ gn2b)
{
    int idx = blockIdx.x * 256 + threadIdx.x;   // 0 .. B*V2*32-1 (group-quad index)
    int v = idx >> 5, g = idx & 31;
    int b = v >> 15;
    float ce   = fmaxf(stats[OFF_CNT2 + b] * 4.f, 1.f);
    float mean = stats[OFF_S1B + b * 32 + g] / ce;
    float var  = stats[OFF_S2B + b * 32 + g] / ce - mean * mean;
    float rinv = rsqrtf(var + 1e-5f);
    float dmv  = dm[v];
    ushort4 hv = *(const ushort4*)(h2a + (size_t)idx * 4);
    float4 gw = *(const float4*)(gn2w + g * 4);
    float4 gb = *(const float4*)(gn2b + g * 4);
    float a, t;
    ushort4 o;
    a = rinv * gw.x; t = (fmaf(bf2f(hv.x), a, gb.x - mean * a)) * dmv; o.x = f2bf(t / (1.f + expf(-t)));
    a = rinv * gw.y; t = (fmaf(bf2f(hv.y), a, gb.y - mean * a)) * dmv; o.y = f2bf(t / (1.f + expf(-t)));
    a = rinv * gw.z; t = (fmaf(bf2f(hv.z), a, gb.z - mean * a)) * dmv; o.z = f2bf(t / (1.f + expf(-t)));
    a = rinv * gw.w; t = (fmaf(bf2f(hv.w), a, gb.w - mean * a)) * dmv; o.w = f2bf(t / (1.f + expf(-t)));
    *(ushort4*)(h2b + (size_t)idx * 4) = o;
}

extern "C" void kernel_launch(void* const* d_in, const int* in_sizes, int n_in,
                              void* d_out, int out_size, void* d_ws, size_t ws_size,
                              hipStream_t stream)
{
    const float* x     = (const float*)d_in[0];
    const int*   mask  = (const int*)d_in[1];
    const float* gn1w  = (const float*)d_in[2];
    const float* gn1b  = (const float*)d_in[3];
    const float* w1    = (const float*)d_in[4];
    const float* b1    = (const float*)d_in[5];
    const float* gn2w  = (const float*)d_in[6];
    const float* gn2b  = (const float*)d_in[7];
    const float* w2    = (const float*)d_in[8];
    const float* b2    = (const float*)d_in[9];
    const float* wskip = (const float*)d_in[10];
    const float* bskip = (const float*)d_in[11];
    float* out = (float*)d_out;

    char* wsb = (char*)d_ws;
    float*          stats = (float*)wsb;                          // 520 f32
    float*          dm    = (float*)(wsb + 4096);                 // 131072 f32
    unsigned short* h1b   = (unsigned short*)(wsb + 528384);      // 131072*64 bf16
    unsigned short* xdb   = (unsigned short*)(wsb + 17305600);    // 131072*64 bf16
    unsigned short* h2a   = (unsigned short*)(wsb + 34082816);    // 131072*128 bf16
    unsigned short* h2b   = (unsigned short*)(wsb + 67637248);    // 131072*128 bf16
    unsigned short* w1t   = (unsigned short*)(wsb + 101191680);   // 54*4096 bf16
    unsigned short* w2t   = (unsigned short*)(wsb + 101634048);   // 110*4096 bf16

    hipMemsetAsync(stats, 0, 520 * sizeof(float), stream);

    hipLaunchKernelGGL(k0_wprep, dim3(2624), dim3(256), 0, stream, w1, w2, wskip, w1t, w2t);
    hipLaunchKernelGGL(k1_stats1, dim3(4096), dim3(256), 0, stream, x, mask, stats);
    hipLaunchKernelGGL(k2_down, dim3(32768), dim3(256), 0, stream,
                       x, mask, gn1w, gn1b, stats, h1b, xdb, dm);
    hipLaunchKernelGGL((conv3_mfma<64, false>), dim3(512), dim3(256), 0, stream,
                       h1b, (const unsigned short*)nullptr, w1t, b1, (const float*)nullptr,
                       dm, (float*)nullptr, h2a);
    hipLaunchKernelGGL(k4_stats2, dim3(4096), dim3(256), 0, stream, h2a, dm, stats);
    hipLaunchKernelGGL(k5_gn2, dim3(16384), dim3(256), 0, stream, h2a, h2b, stats, dm, gn2w, gn2b);
    hipLaunchKernelGGL((conv3_mfma<128, true>), dim3(512), dim3(256), 0, stream,
                       h2b, xdb, w2t, b2, bskip, dm, out, (unsigned short*)nullptr);
}

// Round 4
// 471.444 us; speedup vs baseline: 8.3848x; 1.0080x over previous
//
#include <hip/hip_runtime.h>
#include <cstdint>
#include <cstddef>

#define B_ 4
#define V1 262144   // 64^3
#define C1 64
#define V2 32768    // 32^3
#define C2 128

// stats layout (float indices within stats buffer)
#define OFF_S1A 0
#define OFF_S2A 128
#define OFF_CNT1 256
#define OFF_S1B 260
#define OFF_S2B 388
#define OFF_CNT2 516

typedef __bf16 bf16x8 __attribute__((ext_vector_type(8)));
typedef float f32x4 __attribute__((ext_vector_type(4)));

__device__ __forceinline__ float bf2f(unsigned short u) {
    return __builtin_bit_cast(float, (unsigned)u << 16);
}
__device__ __forceinline__ unsigned short f2bf(float f) {
    unsigned u = __builtin_bit_cast(unsigned, f);
    u += 0x7fffu + ((u >> 16) & 1u);     // RTNE
    return (unsigned short)(u >> 16);
}

// ---------------- Kernel 0: weight prep -> bf16, frag-contiguous slabs [q][n][j] ----------------
// W1T: 54 slabs (27 taps x 2 cslices). W2T: 110 slabs (27x4 conv2 + 2 skip).
__global__ __launch_bounds__(256) void k0_wprep(const float* __restrict__ w1,
                                                const float* __restrict__ w2,
                                                const float* __restrict__ wskip,
                                                unsigned short* __restrict__ w1t,
                                                unsigned short* __restrict__ w2t)
{
    int i = blockIdx.x * 256 + threadIdx.x;
    if (i < 54 * 4096) {
        int slab = i >> 12, r = i & 4095;
        int q = r >> 10, n = (r >> 3) & 127, j = r & 7;
        int t = slab >> 1, s = slab & 1;
        int ci = s * 32 + q * 8 + j;
        w1t[i] = f2bf(w1[((size_t)t * 64 + ci) * 128 + n]);
    }
    int i2 = i - 54 * 4096;
    if (i2 >= 0 && i2 < 110 * 4096) {
        int slab = i2 >> 12, r = i2 & 4095;
        int q = r >> 10, n = (r >> 3) & 127, j = r & 7;
        float v;
        if (slab < 108) {
            int t = slab >> 2, s = slab & 3;
            int ci = s * 32 + q * 8 + j;
            v = w2[((size_t)t * 128 + ci) * 128 + n];
        } else {
            int ci = (slab - 108) * 32 + q * 8 + j;
            v = wskip[(size_t)ci * 128 + n];
        }
        w2t[i2] = f2bf(v);
    }
}

// ---------------- Kernel 1: GN1 stats ----------------
__global__ __launch_bounds__(256) void k1_stats1(const float* __restrict__ x,
                                                 const int* __restrict__ mask,
                                                 float* __restrict__ stats)
{
    __shared__ float ls1[32], ls2[32];
    __shared__ float lcnt;
    int tid = threadIdx.x;
    if (tid < 32) { ls1[tid] = 0.f; ls2[tid] = 0.f; }
    if (tid == 0) lcnt = 0.f;
    __syncthreads();

    int b  = blockIdx.x & 3;
    int bb = blockIdx.x >> 2;
    int c4 = tid & 15;
    int vl = tid >> 4;

    const float* xb = x + ((size_t)b * V1) * C1;
    const int*   mb = mask + (size_t)b * V1;

    float s1a = 0.f, s2a = 0.f, s1b = 0.f, s2b = 0.f, mc = 0.f;
    for (int ch = bb; ch < V1 / 16; ch += 1024) {
        int v = ch * 16 + vl;
        int m = mb[v];
        if (c4 == 0) mc += (float)m;
        if (m) {
            float4 xv = *(const float4*)(xb + (size_t)v * C1 + c4 * 4);
            s1a += xv.x + xv.y;  s2a += xv.x * xv.x + xv.y * xv.y;
            s1b += xv.z + xv.w;  s2b += xv.z * xv.z + xv.w * xv.w;
        }
    }
    atomicAdd(&ls1[2 * c4],     s1a); atomicAdd(&ls2[2 * c4],     s2a);
    atomicAdd(&ls1[2 * c4 + 1], s1b); atomicAdd(&ls2[2 * c4 + 1], s2b);
    if (c4 == 0) atomicAdd(&lcnt, mc);
    __syncthreads();
    if (tid < 32) {
        atomicAdd(&stats[OFF_S1A + b * 32 + tid], ls1[tid]);
        atomicAdd(&stats[OFF_S2A + b * 32 + tid], ls2[tid]);
    }
    if (tid == 0) atomicAdd(&stats[OFF_CNT1 + b], lcnt);
}

// ------ Kernel 2: GN1 apply + SiLU + downsample -> h1b (bf16), xd -> xdb (bf16), dm ------
__global__ __launch_bounds__(256) void k2_down(const float* __restrict__ x,
                                               const int* __restrict__ mask,
                                               const float* __restrict__ gn1w,
                                               const float* __restrict__ gn1b,
                                               const float* __restrict__ stats,
                                               unsigned short* __restrict__ h1b,
                                               unsigned short* __restrict__ xdb,
                                               float* __restrict__ dm)
{
    int tid = threadIdx.x;
    int c  = tid & 63;
    int vl = tid >> 6;
    size_t ov = (size_t)blockIdx.x * 4 + vl;
    int b  = (int)(ov >> 15);
    int v2 = (int)(ov & 32767);
    int z = v2 >> 10, y = (v2 >> 5) & 31, xk = v2 & 31;

    int g = c >> 1;
    float ce   = fmaxf(stats[OFF_CNT1 + b] * 2.f, 1.f);
    float mean = stats[OFF_S1A + b * 32 + g] / ce;
    float var  = stats[OFF_S2A + b * 32 + g] / ce - mean * mean;
    float rinv = rsqrtf(var + 1e-5f);
    float a  = rinv * gn1w[c];
    float bc = gn1b[c] - mean * a;

    const int*   mb = mask + ((size_t)b << 18);
    const float* xb = x + (((size_t)b << 18) << 6);

    float hacc = 0.f, xacc = 0.f; int cnt = 0;
    #pragma unroll
    for (int dz = 0; dz < 2; ++dz)
    #pragma unroll
    for (int dy = 0; dy < 2; ++dy)
    #pragma unroll
    for (int dx = 0; dx < 2; ++dx) {
        int v1 = ((2 * z + dz) << 12) | ((2 * y + dy) << 6) | (2 * xk + dx);
        if (mb[v1]) {
            cnt++;
            float xv = xb[(size_t)v1 * 64 + c];
            xacc += xv;
            float yv = fmaf(xv, a, bc);
            hacc += yv / (1.f + expf(-yv));
        }
    }
    float inv = 1.f / fmaxf((float)cnt, 1.f);
    h1b[ov * 64 + c] = f2bf(hacc * inv);
    xdb[ov * 64 + c] = f2bf(xacc * inv);
    if (c == 0) dm[ov] = (cnt > 0) ? 1.f : 0.f;
}

// ---------------- MFMA implicit-GEMM conv 3x3x3 (+optional 1x1 skip taps) ----------------
// Block: 256 thr = 4 waves. Block tile: M=128 voxels (4 y-rows at one (b,z)), N=128.
// Wave: M=32 (1 y-row), N=128 -> acc[2][8] f32x4 (64 VGPR).
// Pipeline: A-frags prefetched 1 K-step ahead, B-slab 2 K-steps ahead (regs),
// LDS double-buffered; all global loads issued at top of step (full MFMA phase to land).
// Grid 1024 -> 4 blocks/CU = 4 waves/SIMD. Bijective XCD swizzle (chunk 128).
template<int CIN, bool SKIP>
__global__ __launch_bounds__(256, 4) void conv3_mfma(
    const unsigned short* __restrict__ src,
    const unsigned short* __restrict__ sksrc,
    const unsigned short* __restrict__ wT,
    const float* __restrict__ bias,
    const float* __restrict__ bias2,
    const float* __restrict__ dm,
    float* __restrict__ outf,
    unsigned short* __restrict__ outb)
{
    constexpr int CS  = CIN / 32;
    constexpr int NKM = 27 * CS;
    constexpr int NK  = NKM + (SKIP ? 2 : 0);

    __shared__ short smem[2][4096];   // 2 x 8KB weight slabs

    const int tid  = threadIdx.x;
    const int lane = tid & 63;
    const int wv   = tid >> 6;
    // XCD-aware bijective swizzle: 1024 blocks, 8 XCDs, 128-block chunks
    const int orig = blockIdx.x;
    const int blk  = (orig & 7) * 128 + (orig >> 3);
    const int b    = blk >> 8;
    const int z    = (blk >> 3) & 31;
    const int yo   = blk & 7;
    const int y0   = yo * 4 + wv;      // this wave's y-row
    const int vb   = b * 32768;
    const int klo  = (lane >> 4) * 8;
    const int xl   = lane & 15;
    const int rlo  = (lane >> 4) * 4;

    const uint4* wT4 = (const uint4*)wT;
    uint4* sm4 = (uint4*)&smem[0][0];

    f32x4 acc[2][8];
    #pragma unroll
    for (int f = 0; f < 2; ++f)
        #pragma unroll
        for (int nb = 0; nb < 8; ++nb)
            acc[f][nb] = (f32x4){0.f, 0.f, 0.f, 0.f};

    // A-fragment loader for flattened K-step ks (uniform scalar decode)
    auto loadA = [&](int ks, bf16x8 af[2]) {
        const unsigned short* abase;
        int cinl, zz, dy1, dx1;
        if (SKIP && ks >= NKM) {
            abase = sksrc + (ks - NKM) * 32;
            cinl = 64; zz = z; dy1 = 0; dx1 = 0;
        } else {
            int tap = ks / CS, s = ks - tap * CS;       // CS is power of 2
            int dz = tap / 9, r = tap - dz * 9;
            int dy = r / 3,   dx = r - dy * 3;
            abase = src + s * 32;
            cinl = CIN; zz = z + dz - 1; dy1 = dy - 1; dx1 = dx - 1;
        }
        int yy = y0 + dy1;
        bool zyok = ((unsigned)zz < 32u) && ((unsigned)yy < 32u);
        #pragma unroll
        for (int f = 0; f < 2; ++f) {
            int xx = f * 16 + xl + dx1;
            bool ok = zyok && ((unsigned)xx < 32u);
            bf16x8 a = {};
            const unsigned short* ap =
                abase + (size_t)(vb + zz * 1024 + yy * 32 + xx) * (size_t)cinl + klo;
            if (ok) a = *(const bf16x8*)ap;
            af[f] = a;
        }
    };

    // ---- prologue: slab 0 -> LDS, A(0) -> regs, slab 1 -> regs ----
    {
        uint4 p0 = wT4[tid], p1 = wT4[tid + 256];
        sm4[tid] = p0; sm4[tid + 256] = p1;
    }
    bf16x8 afc[2];
    loadA(0, afc);
    uint4 qn0 = {}, qn1 = {};
    if (NK > 1) { qn0 = wT4[512 + tid]; qn1 = wT4[512 + 256 + tid]; }
    __syncthreads();

    int cur = 0;
    #pragma clang loop unroll(disable)
    for (int ks = 0; ks < NK; ++ks) {
        // issue-early: A for ks+1, B slab for ks+2
        bf16x8 afn[2] = {{}, {}};
        if (ks + 1 < NK) loadA(ks + 1, afn);
        uint4 r0 = {}, r1 = {};
        if (ks + 2 < NK) {
            r0 = wT4[(size_t)(ks + 2) * 512 + tid];
            r1 = wT4[(size_t)(ks + 2) * 512 + 256 + tid];
        }
        // MFMA phase: B from LDS[cur], A from regs (loaded last step)
        const int eoffb = cur * 4096 + ((lane >> 4) * 128 + xl) * 8;
        #pragma unroll
        for (int nb = 0; nb < 8; ++nb) {
            bf16x8 bfr = *(const bf16x8*)(&smem[0][0] + eoffb + nb * 128);
            acc[0][nb] = __builtin_amdgcn_mfma_f32_16x16x32_bf16(afc[0], bfr, acc[0][nb], 0, 0, 0);
            acc[1][nb] = __builtin_amdgcn_mfma_f32_16x16x32_bf16(afc[1], bfr, acc[1][nb], 0, 0, 0);
        }
        // write-late: slab ks+1 (loaded 1 step ago, long since arrived)
        if (ks + 1 < NK) {
            sm4[(cur ^ 1) * 512 + tid] = qn0;
            sm4[(cur ^ 1) * 512 + 256 + tid] = qn1;
        }
        __syncthreads();
        afc[0] = afn[0]; afc[1] = afn[1];
        qn0 = r0; qn1 = r1;
        cur ^= 1;
    }

    // ---- epilogue ----
    float bv[8];
    #pragma unroll
    for (int nb = 0; nb < 8; ++nb) {
        int co = nb * 16 + xl;
        if constexpr (SKIP) bv[nb] = bias[co] + bias2[co];
        else                bv[nb] = bias[co];
    }
    #pragma unroll
    for (int f = 0; f < 2; ++f) {
        int xb2 = f * 16 + rlo;
        #pragma unroll
        for (int j = 0; j < 4; ++j) {
            int vox = vb + z * 1024 + y0 * 32 + xb2 + j;
            float dmx = dm[vox];
            #pragma unroll
            for (int nb = 0; nb < 8; ++nb) {
                float o = (acc[f][nb][j] + bv[nb]) * dmx;
                if constexpr (SKIP) outf[(size_t)vox * 128 + nb * 16 + xl] = o;
                else                outb[(size_t)vox * 128 + nb * 16 + xl] = f2bf(o);
            }
        }
    }
}

// ---------------- Kernel 4: GN2 stats over h2a (bf16) ----------------
__global__ __launch_bounds__(256) void k4_stats2(const unsigned short* __restrict__ h2a,
                                                 const float* __restrict__ dm,
                                                 float* __restrict__ stats)
{
    __shared__ float ls1[32], ls2[32];
    __shared__ float lcnt;
    int tid = threadIdx.x;
    if (tid < 32) { ls1[tid] = 0.f; ls2[tid] = 0.f; }
    if (tid == 0) lcnt = 0.f;
    __syncthreads();

    int b  = blockIdx.x & 3;
    int bb = blockIdx.x >> 2;
    int g  = tid & 31;
    int vl = tid >> 5;

    const unsigned short* hb = h2a + ((size_t)b * V2) * C2;
    const float* dmb = dm + (size_t)b * V2;

    float s1 = 0.f, s2 = 0.f, mc = 0.f;
    for (int ch = bb; ch < V2 / 8; ch += 1024) {
        int v = ch * 8 + vl;
        float m = dmb[v];
        if (g == 0) mc += m;
        if (m != 0.f) {
            ushort4 hv = *(const ushort4*)(hb + (size_t)v * C2 + g * 4);
            float h0 = bf2f(hv.x), h1 = bf2f(hv.y), h2 = bf2f(hv.z), h3 = bf2f(hv.w);
            s1 += h0 + h1 + h2 + h3;
            s2 += h0 * h0 + h1 * h1 + h2 * h2 + h3 * h3;
        }
    }
    atomicAdd(&ls1[g], s1); atomicAdd(&ls2[g], s2);
    if (g == 0) atomicAdd(&lcnt, mc);
    __syncthreads();
    if (tid < 32) {
        atomicAdd(&stats[OFF_S1B + b * 32 + tid], ls1[tid]);
        atomicAdd(&stats[OFF_S2B + b * 32 + tid], ls2[tid]);
    }
    if (tid == 0) atomicAdd(&stats[OFF_CNT2 + b], lcnt);
}

// ---------------- Kernel 5: GN2 apply + SiLU -> h2b (bf16) ----------------
__global__ __launch_bounds__(256) void k5_gn2(const unsigned short* __restrict__ h2a,
                                              unsigned short* __restrict__ h2b,
                                              const float* __restrict__ stats,
                                              const float* __restrict__ dm,
                                              const float* __restrict__ gn2w,
                                              const float* __restrict__ gn2b)
{
    int idx = blockIdx.x * 256 + threadIdx.x;   // 0 .. B*V2*32-1 (group-quad index)
    int v = idx >> 5, g = idx & 31;
    int b = v >> 15;
    float ce   = fmaxf(stats[OFF_CNT2 + b] * 4.f, 1.f);
    float mean = stats[OFF_S1B + b * 32 + g] / ce;
    float var  = stats[OFF_S2B + b * 32 + g] / ce - mean * mean;
    float rinv = rsqrtf(var + 1e-5f);
    float dmv  = dm[v];
    ushort4 hv = *(const ushort4*)(h2a + (size_t)idx * 4);
    float4 gw = *(const float4*)(gn2w + g * 4);
    float4 gb = *(const float4*)(gn2b + g * 4);
    float a, t;
    ushort4 o;
    a = rinv * gw.x; t = (fmaf(bf2f(hv.x), a, gb.x - mean * a)) * dmv; o.x = f2bf(t / (1.f + expf(-t)));
    a = rinv * gw.y; t = (fmaf(bf2f(hv.y), a, gb.y - mean * a)) * dmv; o.y = f2bf(t / (1.f + expf(-t)));
    a = rinv * gw.z; t = (fmaf(bf2f(hv.z), a, gb.z - mean * a)) * dmv; o.z = f2bf(t / (1.f + expf(-t)));
    a = rinv * gw.w; t = (fmaf(bf2f(hv.w), a, gb.w - mean * a)) * dmv; o.w = f2bf(t / (1.f + expf(-t)));
    *(ushort4*)(h2b + (size_t)idx * 4) = o;
}

extern "C" void kernel_launch(void* const* d_in, const int* in_sizes, int n_in,
                              void* d_out, int out_size, void* d_ws, size_t ws_size,
                              hipStream_t stream)
{
    const float* x     = (const float*)d_in[0];
    const int*   mask  = (const int*)d_in[1];
    const float* gn1w  = (const float*)d_in[2];
    const float* gn1b  = (const float*)d_in[3];
    const float* w1    = (const float*)d_in[4];
    const float* b1    = (const float*)d_in[5];
    const float* gn2w  = (const float*)d_in[6];
    const float* gn2b  = (const float*)d_in[7];
    const float* w2    = (const float*)d_in[8];
    const float* b2    = (const float*)d_in[9];
    const float* wskip = (const float*)d_in[10];
    const float* bskip = (const float*)d_in[11];
    float* out = (float*)d_out;

    char* wsb = (char*)d_ws;
    float*          stats = (float*)wsb;                          // 520 f32
    float*          dm    = (float*)(wsb + 4096);                 // 131072 f32
    unsigned short* h1b   = (unsigned short*)(wsb + 528384);      // 131072*64 bf16
    unsigned short* xdb   = (unsigned short*)(wsb + 17305600);    // 131072*64 bf16
    unsigned short* h2a   = (unsigned short*)(wsb + 34082816);    // 131072*128 bf16
    unsigned short* h2b   = (unsigned short*)(wsb + 67637248);    // 131072*128 bf16
    unsigned short* w1t   = (unsigned short*)(wsb + 101191680);   // 54*4096 bf16
    unsigned short* w2t   = (unsigned short*)(wsb + 101634048);   // 110*4096 bf16

    hipMemsetAsync(stats, 0, 520 * sizeof(float), stream);

    hipLaunchKernelGGL(k0_wprep, dim3(2624), dim3(256), 0, stream, w1, w2, wskip, w1t, w2t);
    hipLaunchKernelGGL(k1_stats1, dim3(4096), dim3(256), 0, stream, x, mask, stats);
    hipLaunchKernelGGL(k2_down, dim3(32768), dim3(256), 0, stream,
                       x, mask, gn1w, gn1b, stats, h1b, xdb, dm);
    hipLaunchKernelGGL((conv3_mfma<64, false>), dim3(1024), dim3(256), 0, stream,
                       h1b, (const unsigned short*)nullptr, w1t, b1, (const float*)nullptr,
                       dm, (float*)nullptr, h2a);
    hipLaunchKernelGGL(k4_stats2, dim3(4096), dim3(256), 0, stream, h2a, dm, stats);
    hipLaunchKernelGGL(k5_gn2, dim3(16384), dim3(256), 0, stream, h2a, h2b, stats, dm, gn2w, gn2b);
    hipLaunchKernelGGL((conv3_mfma<128, true>), dim3(1024), dim3(256), 0, stream,
                       h2b, xdb, w2t, b2, bskip, dm, out, (unsigned short*)nullptr);
}